// Round 3
// baseline (265.036 us; speedup 1.0000x reference)
//
#include <hip/hip_runtime.h>
#include <hip/hip_bf16.h>
#include <math.h>

constexpr int N   = 4096;   // nodes
constexpr int F   = 256;    // IN_FEAT (= NH*HID)
constexpr int NH  = 8;      // heads
constexpr int HID = 32;     // hidden per head
constexpr float SLOPE = 0.2f;

using frag_ab = __attribute__((ext_vector_type(8))) short;  // 8 bf16
using frag_cd = __attribute__((ext_vector_type(4))) float;  // 4 fp32

__device__ inline unsigned short f2bf(float x) {  // RNE fp32->bf16
  unsigned int u = __float_as_uint(x);
  unsigned int r = (u + 0x7fffu + ((u >> 16) & 1u)) >> 16;
  return (unsigned short)r;
}

// ---------------- K1: g = h @ W^T (fp32) ----------------
// 256 blocks x 512 thr; 16 rows/block; thread owns 2 rows x 4 cols.
// W staged in LDS per 32-k chunk (padded stride 36 -> balanced b128 banks).
__global__ __launch_bounds__(512) void k_gemm(const float* __restrict__ h,
                                              const float* __restrict__ W,
                                              float* __restrict__ g) {
  __shared__ float hs[16][260];
  __shared__ float Ws[256][36];
  const int t  = threadIdx.x;
  const int i0 = blockIdx.x * 16;
  {  // stage h tile: 16 x 256 = 4096 floats, 8 per thread
    const int hr = t >> 5, hc = (t & 31) * 8;
    const float4* src = (const float4*)(h + (size_t)(i0 + hr) * F + hc);
    *(float4*)&hs[hr][hc]     = src[0];
    *(float4*)&hs[hr][hc + 4] = src[1];
  }
  const int c  = t & 63;   // output col group
  const int rg = t >> 6;   // row group (0..7) -> rows rg*2, rg*2+1
  float acc[2][4];
#pragma unroll
  for (int r = 0; r < 2; ++r)
#pragma unroll
    for (int q = 0; q < 4; ++q) acc[r][q] = 0.f;

  for (int kc = 0; kc < 8; ++kc) {
    __syncthreads();
    // stage W slab: 256 rows x 32 k-cols = 2048 float4, 4 per thread
#pragma unroll
    for (int p = 0; p < 4; ++p) {
      const int f4 = p * 512 + t;
      const int row = f4 >> 3, q4 = f4 & 7;
      *(float4*)&Ws[row][q4 * 4] =
          *(const float4*)(W + (size_t)row * F + kc * 32 + q4 * 4);
    }
    __syncthreads();
#pragma unroll
    for (int k8 = 0; k8 < 8; ++k8) {
      float4 wv[4], hv[2];
#pragma unroll
      for (int q = 0; q < 4; ++q) wv[q] = *(const float4*)&Ws[c + 64 * q][k8 * 4];
#pragma unroll
      for (int r = 0; r < 2; ++r) hv[r] = *(const float4*)&hs[rg * 2 + r][kc * 32 + k8 * 4];
#pragma unroll
      for (int r = 0; r < 2; ++r)
#pragma unroll
        for (int q = 0; q < 4; ++q) {
          acc[r][q] += hv[r].x * wv[q].x + hv[r].y * wv[q].y +
                       hv[r].z * wv[q].z + hv[r].w * wv[q].w;
        }
    }
  }
#pragma unroll
  for (int r = 0; r < 2; ++r)
#pragma unroll
    for (int q = 0; q < 4; ++q)
      g[(size_t)(i0 + rg * 2 + r) * F + c + 64 * q] = acc[r][q];
}

// ---------------- K1b: transpose g -> gT (bf16) ----------------
// tile 64 j x 64 f; read coalesced, LDS, write gT rows coalesced.
__global__ __launch_bounds__(256) void k_tr(const float* __restrict__ g,
                                            unsigned short* __restrict__ gT) {
  __shared__ float sT[64][68];
  const int t  = threadIdx.x;
  const int j0 = blockIdx.x * 64;
  const int f0 = blockIdx.y * 64;
  const int jr = t >> 2, q = t & 3;
#pragma unroll
  for (int u = 0; u < 4; ++u) {
    *(float4*)&sT[jr][(u * 4 + q) * 4] =
        *(const float4*)(g + (size_t)(j0 + jr) * F + f0 + (u * 4 + q) * 4);
  }
  __syncthreads();
  const int fr = t >> 2, jq = t & 3;
  unsigned short tmp[16];
#pragma unroll
  for (int u = 0; u < 16; ++u) tmp[u] = f2bf(sT[jq * 16 + u][fr]);
  *(int4*)(gT + (size_t)(f0 + fr) * N + j0 + jq * 16)     = *(int4*)tmp;
  *(int4*)(gT + (size_t)(f0 + fr) * N + j0 + jq * 16 + 8) = *(int4*)(tmp + 8);
}

// ---------------- K2: s_i, s_j, exp(s_j), exp(0.2 s_j) ----------------
__global__ __launch_bounds__(256) void k_sisj(const float* __restrict__ g,
                                              const float* __restrict__ a,
                                              float* __restrict__ si,
                                              float* __restrict__ sj,
                                              float* __restrict__ sjB,
                                              float* __restrict__ sjD) {
  const int idx = blockIdx.x * 256 + threadIdx.x;  // n*8 + h
  const int n = idx >> 3, hh = idx & 7;
  const float4* gp = (const float4*)(g + (size_t)n * F + hh * HID);
  const float4* al = (const float4*)a;
  const float4* ar = (const float4*)(a + HID);
  float sl = 0.f, sr = 0.f;
#pragma unroll
  for (int q = 0; q < HID / 4; ++q) {
    const float4 gv = gp[q];
    const float4 av = al[q], bv = ar[q];
    sl += gv.x * av.x + gv.y * av.y + gv.z * av.z + gv.w * av.w;
    sr += gv.x * bv.x + gv.y * bv.y + gv.z * bv.z + gv.w * bv.w;
  }
  si[idx] = sl;
  sj[idx] = sr;
  sjB[idx] = __expf(sr);
  sjD[idx] = __expf(SLOPE * sr);
}

// ---------------- K3: masked max over s_j (tiled) + bitmask pack ----------------
// block = 32 i x 1024-j strip; sj staged in LDS once; masked max via
// address-select into a -inf LDS row (1 cmp + 1 cndmask + 8 fmax / 64 j).
__global__ __launch_bounds__(512) void k_maxbits(const int* __restrict__ adj,
                                                 const float* __restrict__ sj,
                                                 unsigned int* __restrict__ bits,
                                                 float* __restrict__ pmax) {
  __shared__ float sj4[1024 * 8 + 8];
  const int t    = threadIdx.x;
  const int lane = t & 63;
  const int w    = t >> 6;  // 8 waves
  const int i0   = blockIdx.x * 32;
  const int j0   = blockIdx.y * 1024;
#pragma unroll
  for (int p = 0; p < 4; ++p) {
    const int idx4 = p * 512 + t;
    *(float4*)&sj4[idx4 * 4] = *(const float4*)(sj + (size_t)j0 * 8 + idx4 * 4);
  }
  if (t < 8) sj4[8192 + t] = -INFINITY;
  __syncthreads();

  for (int rr = 0; rr < 4; ++rr) {
    const int i = i0 + w * 4 + rr;
    const int* arow = adj + (size_t)i * N + j0;
    float pm[8];
#pragma unroll
    for (int hh = 0; hh < 8; ++hh) pm[hh] = -INFINITY;
#pragma unroll
    for (int c = 0; c < 16; ++c) {
      const int j = c * 64 + lane;
      const bool bit = arow[j] != 0;
      const unsigned long long bal = __ballot(bit);
      if (lane == 0) {
        *(unsigned long long*)(bits + (size_t)i * (N / 32) + (j0 >> 5) + 2 * c) = bal;
      }
      const int je = bit ? j : 1024;  // -inf row when not a neighbor
      const float4 s0 = *(const float4*)&sj4[je * 8];
      const float4 s1 = *(const float4*)&sj4[je * 8 + 4];
      pm[0] = fmaxf(pm[0], s0.x); pm[1] = fmaxf(pm[1], s0.y);
      pm[2] = fmaxf(pm[2], s0.z); pm[3] = fmaxf(pm[3], s0.w);
      pm[4] = fmaxf(pm[4], s1.x); pm[5] = fmaxf(pm[5], s1.y);
      pm[6] = fmaxf(pm[6], s1.z); pm[7] = fmaxf(pm[7], s1.w);
    }
#pragma unroll
    for (int hh = 0; hh < 8; ++hh) {
#pragma unroll
      for (int o = 1; o < 64; o <<= 1) pm[hh] = fmaxf(pm[hh], __shfl_xor(pm[hh], o));
    }
    if (lane == 0) {
      float* dst = pmax + ((size_t)blockIdx.y * N + i) * 8;
      *(float4*)dst       = make_float4(pm[0], pm[1], pm[2], pm[3]);
      *(float4*)(dst + 4) = make_float4(pm[4], pm[5], pm[6], pm[7]);
    }
  }
}

// ---------------- K3b: combine strips, m = lrelu(si + max) ----------------
__global__ __launch_bounds__(256) void k_finish(const float* __restrict__ pmax,
                                                const float* __restrict__ si,
                                                float* __restrict__ m) {
  const int idx = blockIdx.x * 256 + threadIdx.x;  // i*8+h, 32768 total
  const float v = fmaxf(fmaxf(pmax[idx], pmax[32768 + idx]),
                        fmaxf(pmax[65536 + idx], pmax[98304 + idx]));
  const float x = si[idx] + v;
  m[idx] = fmaxf(x, SLOPE * x);
}

// ---------------- K4: MFMA flash-style aggregation ----------------
// w = adj * (x>0 ? A_i*B_j : C_i*D_j) -- no exp in the loop; sign test via
// B_j > exp(-s_i) (exp monotone). l via MFMA against ones-fragment.
constexpr int TI = 32;
constexpr int JC = 128;

__global__ __launch_bounds__(256, 2) void k_agg(
    const unsigned short* __restrict__ gT,
    const float* __restrict__ si, const float* __restrict__ m,
    const float* __restrict__ sjB, const float* __restrict__ sjD,
    const unsigned int* __restrict__ bits,
    float* __restrict__ out) {
  __shared__ __align__(16) unsigned short sB[64][136];  // gT chunk: row=f, col=j
  __shared__ __align__(16) float sBv[2][JC];
  __shared__ __align__(16) float sDv[2][JC];
  __shared__ unsigned int sBits[TI][JC / 32];

  const int t    = threadIdx.x;
  const int lane = t & 63;
  const int wv   = t >> 6;
  const int isub = wv & 1;
  const int hh   = wv >> 1;
  const int hp   = blockIdx.x & 3;
  const int i0   = (blockIdx.x >> 2) * TI;
  const int head = hp * 2 + hh;

  const int n16  = lane & 15;
  const int quad = lane >> 4;

  const int myi   = i0 + isub * 16 + n16;
  const float siv = si[(size_t)myi * 8 + head];
  const float mv  = m[(size_t)myi * 8 + head];
  const float Ai  = __expf(siv - mv);
  const float Ci  = __expf(SLOPE * siv - mv);
  const float Ti  = __expf(-siv);

  frag_cd acc0 = {0.f, 0.f, 0.f, 0.f};
  frag_cd acc1 = {0.f, 0.f, 0.f, 0.f};
  frag_cd accl = {0.f, 0.f, 0.f, 0.f};
  frag_ab fone;
#pragma unroll
  for (int u = 0; u < 8; ++u) fone[u] = (short)0x3F80;  // bf16 1.0

  const int sr = t >> 2, ss0 = t & 3;  // gT staging persona

  for (int c = 0; c < N / JC; ++c) {
    const int j0 = c * JC;
    __syncthreads();
    {  // stage gT rows (64 x 128 bf16)
      const unsigned short* src = gT + (size_t)(hp * 64 + sr) * N + j0;
#pragma unroll
      for (int s = 0; s < 4; ++s) {
        const int seg = ss0 + s * 4;
        *(int4*)&sB[sr][seg * 8] = *(const int4*)(src + seg * 8);
      }
    }
    {  // stage exp(sj), exp(0.2 sj) for the head pair
      const int jj = t >> 1, hs = t & 1;
      sBv[hs][jj] = sjB[(size_t)(j0 + jj) * 8 + hp * 2 + hs];
      sDv[hs][jj] = sjD[(size_t)(j0 + jj) * 8 + hp * 2 + hs];
    }
    if (t < TI * (JC / 32)) {  // stage bits chunk
      const int ir = t >> 2, wd = t & 3;
      sBits[ir][wd] = bits[(size_t)(i0 + ir) * (N / 32) + (j0 >> 5) + wd];
    }
    __syncthreads();
#pragma unroll
    for (int ks = 0; ks < JC / 32; ++ks) {
      const int jb = ks * 32 + quad * 8;
      const unsigned int word = sBits[isub * 16 + n16][ks];
      const float4 B0 = *(const float4*)&sBv[hh][jb];
      const float4 B1 = *(const float4*)&sBv[hh][jb + 4];
      const float4 D0 = *(const float4*)&sDv[hh][jb];
      const float4 D1 = *(const float4*)&sDv[hh][jb + 4];
      const float Bu[8] = {B0.x, B0.y, B0.z, B0.w, B1.x, B1.y, B1.z, B1.w};
      const float Du[8] = {D0.x, D0.y, D0.z, D0.w, D1.x, D1.y, D1.z, D1.w};
      int packed[4];
#pragma unroll
      for (int p = 0; p < 4; ++p) {
        float wvv[2];
#pragma unroll
        for (int q = 0; q < 2; ++q) {
          const int u = p * 2 + q;
          const bool pos = Bu[u] > Ti;
          const float fi = pos ? Ai : Ci;
          const float fj = pos ? Bu[u] : Du[u];
          const float ww = fi * fj;
          wvv[q] = ((word >> (quad * 8 + u)) & 1u) ? ww : 0.f;
        }
        __hip_bfloat162 bp = __float22bfloat162_rn(make_float2(wvv[0], wvv[1]));
        __builtin_memcpy(&packed[p], &bp, 4);
      }
      frag_ab af;
      __builtin_memcpy(&af, packed, 16);
      const frag_ab b0 = *(const frag_ab*)&sB[hh * 32 + n16][jb];
      const frag_ab b1 = *(const frag_ab*)&sB[hh * 32 + 16 + n16][jb];
      acc0 = __builtin_amdgcn_mfma_f32_16x16x32_bf16(af, b0, acc0, 0, 0, 0);
      acc1 = __builtin_amdgcn_mfma_f32_16x16x32_bf16(af, b1, acc1, 0, 0, 0);
      accl = __builtin_amdgcn_mfma_f32_16x16x32_bf16(af, fone, accl, 0, 0, 0);
    }
  }
  // epilogue: C layout col=n16, row=quad*4+reg; accl holds row sums (l_i)
#pragma unroll
  for (int reg = 0; reg < 4; ++reg) {
    const int row = quad * 4 + reg;
    const float inv = 1.f / accl[reg];
    const int gi = i0 + isub * 16 + row;
    out[(size_t)gi * F + head * HID + n16]      = acc0[reg] * inv;
    out[(size_t)gi * F + head * HID + 16 + n16] = acc1[reg] * inv;
  }
}

extern "C" void kernel_launch(void* const* d_in, const int* in_sizes, int n_in,
                              void* d_out, int out_size, void* d_ws, size_t ws_size,
                              hipStream_t stream) {
  const float* h   = (const float*)d_in[0];
  const float* W   = (const float*)d_in[1];
  const float* a   = (const float*)d_in[2];
  const int*   adj = (const int*)d_in[3];
  float* out = (float*)d_out;

  // workspace: g (4MB, later aliased by pmax 512KB) | si,sj,m,sjB,sjD (640KB)
  //            | bits (2MB) | gT (2MB)   -> ~8.63 MB
  float* wsf = (float*)d_ws;
  float* g    = wsf;
  float* pmax = wsf;                       // alias: g dead after k_tr/k_sisj
  float* si   = g  + (size_t)N * F;
  float* sj   = si + (size_t)N * NH;
  float* m    = sj + (size_t)N * NH;
  float* sjB  = m  + (size_t)N * NH;
  float* sjD  = sjB + (size_t)N * NH;
  unsigned int* bits = (unsigned int*)(sjD + (size_t)N * NH);
  unsigned short* gT = (unsigned short*)(bits + (size_t)N * (N / 32));

  k_gemm<<<dim3(N / 16), dim3(512), 0, stream>>>(h, W, g);
  k_sisj<<<dim3(N * NH / 256), dim3(256), 0, stream>>>(g, a, si, sj, sjB, sjD);
  k_tr<<<dim3(N / 64, F / 64), dim3(256), 0, stream>>>(g, gT);
  k_maxbits<<<dim3(N / 32, 4), dim3(512), 0, stream>>>(adj, sj, bits, pmax);
  k_finish<<<dim3(N * NH / 256), dim3(256), 0, stream>>>(pmax, si, m);
  k_agg<<<dim3((N / TI) * 4), dim3(256), 0, stream>>>(gT, si, m, sjB, sjD, bits, out);
}

// Round 4
// 203.039 us; speedup vs baseline: 1.3053x; 1.3053x over previous
//
#include <hip/hip_runtime.h>
#include <hip/hip_bf16.h>
#include <math.h>

constexpr int N   = 4096;   // nodes
constexpr int F   = 256;    // IN_FEAT (= NH*HID)
constexpr int NH  = 8;      // heads
constexpr int HID = 32;     // hidden per head
constexpr float SLOPE = 0.2f;

using frag_ab = __attribute__((ext_vector_type(8))) short;  // 8 bf16
using frag_cd = __attribute__((ext_vector_type(4))) float;  // 4 fp32

__device__ inline unsigned short f2bf(float x) {  // RNE fp32->bf16
  unsigned int u = __float_as_uint(x);
  unsigned int r = (u + 0x7fffu + ((u >> 16) & 1u)) >> 16;
  return (unsigned short)r;
}

// ---------------- K0: cast h and W to bf16 ----------------
// 8 elements/thread; hb (1M elems) then Wb (64K) contiguous.
__global__ __launch_bounds__(256) void k_cast(const float* __restrict__ h,
                                              const float* __restrict__ W,
                                              unsigned short* __restrict__ hb) {
  const int idx8 = (blockIdx.x * 256 + threadIdx.x) * 8;
  const float* src = (idx8 < N * F) ? (h + idx8) : (W + idx8 - N * F);
  const float4 v0 = *(const float4*)src;
  const float4 v1 = *(const float4*)(src + 4);
  unsigned short tmp[8];
  tmp[0] = f2bf(v0.x); tmp[1] = f2bf(v0.y); tmp[2] = f2bf(v0.z); tmp[3] = f2bf(v0.w);
  tmp[4] = f2bf(v1.x); tmp[5] = f2bf(v1.y); tmp[6] = f2bf(v1.z); tmp[7] = f2bf(v1.w);
  *(int4*)(hb + idx8) = *(int4*)tmp;
}

// ---------------- K1: g = h @ W^T via MFMA (bf16 in, fp32 out) ----------------
// one wave per 16x16 output tile; frags loaded straight from global (L1/L2-hot).
__global__ __launch_bounds__(256) void k_mm(const unsigned short* __restrict__ hb,
                                            const unsigned short* __restrict__ Wb,
                                            float* __restrict__ g) {
  const int t    = threadIdx.x;
  const int lane = t & 63;
  const int tile = blockIdx.x * 4 + (t >> 6);
  const int mt   = tile >> 4, nt = tile & 15;
  const int m0 = mt * 16, n0 = nt * 16;
  const int n16 = lane & 15, quad = lane >> 4;
  frag_cd acc = {0.f, 0.f, 0.f, 0.f};
  const unsigned short* ap = hb + (size_t)(m0 + n16) * F + quad * 8;
  const unsigned short* bp = Wb + (size_t)(n0 + n16) * F + quad * 8;
#pragma unroll
  for (int ks = 0; ks < F / 32; ++ks) {
    const frag_ab af = *(const frag_ab*)(ap + ks * 32);
    const frag_ab bf = *(const frag_ab*)(bp + ks * 32);
    acc = __builtin_amdgcn_mfma_f32_16x16x32_bf16(af, bf, acc, 0, 0, 0);
  }
#pragma unroll
  for (int reg = 0; reg < 4; ++reg) {
    g[(size_t)(m0 + quad * 4 + reg) * F + n0 + n16] = acc[reg];
  }
}

// ---------------- K1b: transpose g -> gT (bf16) ----------------
__global__ __launch_bounds__(256) void k_tr(const float* __restrict__ g,
                                            unsigned short* __restrict__ gT) {
  __shared__ float sT[64][68];
  const int t  = threadIdx.x;
  const int j0 = blockIdx.x * 64;
  const int f0 = blockIdx.y * 64;
  const int jr = t >> 2, q = t & 3;
#pragma unroll
  for (int u = 0; u < 4; ++u) {
    *(float4*)&sT[jr][(u * 4 + q) * 4] =
        *(const float4*)(g + (size_t)(j0 + jr) * F + f0 + (u * 4 + q) * 4);
  }
  __syncthreads();
  const int fr = t >> 2, jq = t & 3;
  unsigned short tmp[16];
#pragma unroll
  for (int u = 0; u < 16; ++u) tmp[u] = f2bf(sT[jq * 16 + u][fr]);
  *(int4*)(gT + (size_t)(f0 + fr) * N + j0 + jq * 16)     = *(int4*)tmp;
  *(int4*)(gT + (size_t)(f0 + fr) * N + j0 + jq * 16 + 8) = *(int4*)(tmp + 8);
}

// ---------------- K2: s_i, s_j, bf16 B^T/D^T ----------------
__global__ __launch_bounds__(256) void k_sisj(const float* __restrict__ g,
                                              const float* __restrict__ a,
                                              float* __restrict__ si,
                                              float* __restrict__ sj,
                                              unsigned short* __restrict__ BT,
                                              unsigned short* __restrict__ DT) {
  const int idx = blockIdx.x * 256 + threadIdx.x;  // n*8 + h
  const int n = idx >> 3, hh = idx & 7;
  const float4* gp = (const float4*)(g + (size_t)n * F + hh * HID);
  const float4* al = (const float4*)a;
  const float4* ar = (const float4*)(a + HID);
  float sl = 0.f, sr = 0.f;
#pragma unroll
  for (int q = 0; q < HID / 4; ++q) {
    const float4 gv = gp[q];
    const float4 av = al[q], bv = ar[q];
    sl += gv.x * av.x + gv.y * av.y + gv.z * av.z + gv.w * av.w;
    sr += gv.x * bv.x + gv.y * bv.y + gv.z * bv.z + gv.w * bv.w;
  }
  si[idx] = sl;
  sj[idx] = sr;
  BT[(size_t)hh * N + n] = f2bf(__expf(sr));
  DT[(size_t)hh * N + n] = f2bf(__expf(SLOPE * sr));
}

// ---------------- K2b: per-head global max of s_j (unmasked) ----------------
// m = lrelu(si + M_h) is a valid flash-softmax shift (upper bound, exact math).
__global__ __launch_bounds__(256) void k_mh(const float* __restrict__ sj,
                                            float* __restrict__ M) {
  __shared__ float red[8][32];
  const int t = threadIdx.x;
  const int hh = t >> 5, part = t & 31;
  float mx = -INFINITY;
  for (int k = 0; k < N / 32; ++k) {
    mx = fmaxf(mx, sj[(size_t)(part * (N / 32) + k) * 8 + hh]);
  }
  red[hh][part] = mx;
  __syncthreads();
  if (t < 8) {
    float v = -INFINITY;
#pragma unroll
    for (int p = 0; p < 32; ++p) v = fmaxf(v, red[t][p]);
    M[t] = v;
  }
}

// ---------------- K3: adjacency bitmask (pure ballot, HBM-bound) ----------------
__global__ __launch_bounds__(256) void k_bits(const int* __restrict__ adj,
                                              unsigned int* __restrict__ bits) {
  const int t = threadIdx.x, lane = t & 63, wv = t >> 6;
  const int row = blockIdx.x * 4 + wv;
  const int4* arow = (const int4*)(adj + (size_t)row * N);
#pragma unroll
  for (int c = 0; c < 16; ++c) {
    const int4 av = arow[c * 64 + lane];
    unsigned int v = (av.x != 0 ? 1u : 0u) | (av.y != 0 ? 2u : 0u) |
                     (av.z != 0 ? 4u : 0u) | (av.w != 0 ? 8u : 0u);
    v <<= ((lane & 7) * 4);
    v |= __shfl_xor(v, 1);
    v |= __shfl_xor(v, 2);
    v |= __shfl_xor(v, 4);
    if ((lane & 7) == 0) bits[(size_t)row * (N / 32) + c * 8 + (lane >> 3)] = v;
  }
}

// ---------------- K4: MFMA flash aggregation, j-split x4, atomic partials ----------------
constexpr int TI = 32;
constexpr int JC = 128;
constexpr int NSPLIT = 4;

__global__ __launch_bounds__(256, 6) void k_agg(
    const unsigned short* __restrict__ gT,
    const float* __restrict__ si, const float* __restrict__ M,
    const unsigned short* __restrict__ BT, const unsigned short* __restrict__ DT,
    const unsigned int* __restrict__ bits,
    float* __restrict__ outp, float* __restrict__ lbuf) {
  __shared__ __align__(16) unsigned short sB[64][136];  // gT chunk: row=f(pair), col=j

  const int t    = threadIdx.x;
  const int lane = t & 63;
  const int wv   = t >> 6;
  const int isub = wv & 1;
  const int hh   = wv >> 1;
  const int b    = blockIdx.x;
  const int hp   = b & 3;
  const int js   = (b >> 2) & (NSPLIT - 1);
  const int i0   = (b >> 4) * TI;
  const int head = hp * 2 + hh;

  const int n16  = lane & 15;
  const int quad = lane >> 4;

  const int myi   = i0 + isub * 16 + n16;
  const float siv = si[(size_t)myi * NH + head];
  const float Mh  = M[head];
  const float xm  = siv + Mh;
  const float mv  = fmaxf(xm, SLOPE * xm);
  const float Ai  = __expf(siv - mv);
  const float Ci  = __expf(SLOPE * siv - mv);

  frag_cd acc0 = {0.f, 0.f, 0.f, 0.f};
  frag_cd acc1 = {0.f, 0.f, 0.f, 0.f};
  frag_cd accl = {0.f, 0.f, 0.f, 0.f};
  frag_ab fone;
#pragma unroll
  for (int u = 0; u < 8; ++u) fone[u] = (short)0x3F80;  // bf16 1.0

  const unsigned short* BTh = BT + (size_t)head * N;
  const unsigned short* DTh = DT + (size_t)head * N;
  const int sr = t >> 2, ss0 = t & 3;  // gT staging persona

  for (int c = 0; c < 1024 / JC; ++c) {
    const int j0 = js * 1024 + c * JC;
    __syncthreads();
    {  // stage gT rows (64 x 128 bf16)
      const unsigned short* src = gT + (size_t)(hp * 64 + sr) * N + j0;
#pragma unroll
      for (int s = 0; s < 4; ++s) {
        const int seg = ss0 + s * 4;
        *(int4*)&sB[sr][seg * 8] = *(const int4*)(src + seg * 8);
      }
    }
    const uint4 bw = *(const uint4*)(bits + (size_t)myi * (N / 32) + (j0 >> 5));
    __syncthreads();
#pragma unroll
    for (int ks = 0; ks < JC / 32; ++ks) {
      const int jb = ks * 32 + quad * 8;
      const uint4 Bu = *(const uint4*)(BTh + j0 + jb);  // 8 bf16
      const uint4 Du = *(const uint4*)(DTh + j0 + jb);
      const unsigned int wrd = ks == 0 ? bw.x : ks == 1 ? bw.y : ks == 2 ? bw.z : bw.w;
      const unsigned int mb = (wrd >> (quad * 8)) & 0xffu;
      const unsigned int bu[4] = {Bu.x, Bu.y, Bu.z, Bu.w};
      const unsigned int du[4] = {Du.x, Du.y, Du.z, Du.w};
      int packed[4];
#pragma unroll
      for (int p = 0; p < 4; ++p) {
        const float b0f = __uint_as_float(bu[p] << 16);
        const float b1f = __uint_as_float(bu[p] & 0xffff0000u);
        const float d0f = __uint_as_float(du[p] << 16);
        const float d1f = __uint_as_float(du[p] & 0xffff0000u);
        float w0 = fmaxf(Ai * b0f, Ci * d0f);   // exp(lrelu(si+sj)-m)
        float w1 = fmaxf(Ai * b1f, Ci * d1f);
        w0 = (mb & (1u << (2 * p)))     ? w0 : 0.f;
        w1 = (mb & (1u << (2 * p + 1))) ? w1 : 0.f;
        __hip_bfloat162 bp2 = __float22bfloat162_rn(make_float2(w0, w1));
        __builtin_memcpy(&packed[p], &bp2, 4);
      }
      frag_ab af;
      __builtin_memcpy(&af, packed, 16);
      const frag_ab b0 = *(const frag_ab*)&sB[hh * 32 + n16][jb];
      const frag_ab b1 = *(const frag_ab*)&sB[hh * 32 + 16 + n16][jb];
      acc0 = __builtin_amdgcn_mfma_f32_16x16x32_bf16(af, b0, acc0, 0, 0, 0);
      acc1 = __builtin_amdgcn_mfma_f32_16x16x32_bf16(af, b1, acc1, 0, 0, 0);
      accl = __builtin_amdgcn_mfma_f32_16x16x32_bf16(af, fone, accl, 0, 0, 0);
    }
  }
  // epilogue: C layout col=n16, row=quad*4+reg; atomic partial accumulation
#pragma unroll
  for (int reg = 0; reg < 4; ++reg) {
    const int row = quad * 4 + reg;
    const int gi = i0 + isub * 16 + row;
    atomicAdd(&outp[(size_t)gi * F + head * HID + n16], acc0[reg]);
    atomicAdd(&outp[(size_t)gi * F + head * HID + 16 + n16], acc1[reg]);
    if (n16 == 0) atomicAdd(&lbuf[(size_t)gi * NH + head], accl[reg]);
  }
}

// ---------------- K5: normalize ----------------
__global__ __launch_bounds__(256) void k_norm(float* __restrict__ outp,
                                              const float* __restrict__ lbuf) {
  const int idx = blockIdx.x * 256 + threadIdx.x;  // float4 index
  const int i = idx >> 6, fq = idx & 63;
  const int hh = fq >> 3;
  const float inv = 1.f / lbuf[(size_t)i * NH + hh];
  float4 v = *(float4*)(outp + (size_t)idx * 4);
  v.x *= inv; v.y *= inv; v.z *= inv; v.w *= inv;
  *(float4*)(outp + (size_t)idx * 4) = v;
}

extern "C" void kernel_launch(void* const* d_in, const int* in_sizes, int n_in,
                              void* d_out, int out_size, void* d_ws, size_t ws_size,
                              hipStream_t stream) {
  const float* h   = (const float*)d_in[0];
  const float* W   = (const float*)d_in[1];
  const float* a   = (const float*)d_in[2];
  const int*   adj = (const int*)d_in[3];
  float* out = (float*)d_out;

  // workspace layout (~8.8 MB)
  char* ws = (char*)d_ws;
  float* g = (float*)ws;                      ws += (size_t)N * F * 4;        // 4 MB
  unsigned short* hb = (unsigned short*)ws;   ws += (size_t)(N * F + F * F) * 2;  // 2.13 MB
  unsigned short* Wb = hb + (size_t)N * F;
  unsigned short* gT = (unsigned short*)ws;   ws += (size_t)N * F * 2;        // 2 MB
  unsigned int* bits = (unsigned int*)ws;     ws += (size_t)N * (N / 32) * 4; // 2 MB  -- wait, adjust below
  float* si = (float*)ws;                     ws += (size_t)N * NH * 4;
  float* sj = (float*)ws;                     ws += (size_t)N * NH * 4;
  unsigned short* BT = (unsigned short*)ws;   ws += (size_t)NH * N * 2;
  unsigned short* DT = (unsigned short*)ws;   ws += (size_t)NH * N * 2;
  float* lbuf = (float*)ws;                   ws += (size_t)N * NH * 4;
  float* M = (float*)ws;                      ws += 64;

  hipMemsetAsync(out, 0, (size_t)N * F * 4, stream);
  hipMemsetAsync(lbuf, 0, (size_t)N * NH * 4, stream);

  k_cast<<<dim3((N * F + F * F) / (256 * 8)), dim3(256), 0, stream>>>(h, W, hb);
  k_mm<<<dim3((N / 16) * (F / 16) / 4), dim3(256), 0, stream>>>(hb, Wb, g);
  k_tr<<<dim3(N / 64, F / 64), dim3(256), 0, stream>>>(g, gT);
  k_sisj<<<dim3(N * NH / 256), dim3(256), 0, stream>>>(g, a, si, sj, BT, DT);
  k_mh<<<dim3(1), dim3(256), 0, stream>>>(sj, M);
  k_bits<<<dim3(N / 4), dim3(256), 0, stream>>>(adj, bits);
  k_agg<<<dim3((N / TI) * 4 * NSPLIT), dim3(256), 0, stream>>>(
      gT, si, M, BT, DT, bits, out, lbuf);
  k_norm<<<dim3(N * F / 4 / 256), dim3(256), 0, stream>>>(out, lbuf);
}